// Round 1
// 70.904 us; speedup vs baseline: 1.0069x; 1.0069x over previous
//
#include <hip/hip_runtime.h>

// AllZeroDigitalFilter: time-varying FIR with linearly-interpolated coefficients.
//   out[b,t] = sum_{k=0..255} x[b,t-k] * ((1-f)*h[b,n,k] + f*h[b,n1,k])
//   n = t/80, f = (t%80)/80, n1 = min(n+1, N-1), x[neg] = 0
// B=8, N=800, P=80, T=64000, TAPS=256.
//
// v2: K-split x2 (128 taps/thread, LDS combine) doubles occupancy to ~3.1
// waves/SIMD; 8-tap register-rotated x window cuts LDS reads to 1/tap.

#define TAPS 256
#define PP 80
#define BB 8
#define NN 800
#define TT (NN * PP)
#define FPB 4                       // frames per block
#define TPF 16                      // lanes per frame
#define RR 5                        // outputs per thread (TPF*RR == PP)
#define KSPLIT 2
#define KTH (TAPS / KSPLIT)         // 128 taps per thread
#define NTHREADS (KSPLIT * FPB * TPF)   // 128 (2 waves: wave0=kh0, wave1=kh1)
#define HSTRIDE 260                 // 256 + 4: frame rows offset by 4 banks
#define XWIN (FPB * PP + TAPS - 1)  // 575
#define CHUNKS (NN / FPB)           // 200

__global__ __launch_bounds__(NTHREADS, 4) void azdf_kernel(
    const float* __restrict__ x, const float* __restrict__ h,
    float* __restrict__ out)
{
    __shared__ float sh[(FPB + 1) * HSTRIDE];     // 5 rows  = 5200 B
    __shared__ float sx[XWIN + 1];                // 2304 B
    __shared__ float red[FPB * TPF * 2 * RR];     // 2560 B  (kh1 partials)

    const int tid = threadIdx.x;
    const int blk = blockIdx.x;
    const int b   = blk / CHUNKS;
    const int nc  = blk % CHUNKS;
    const int n0  = nc * FPB;
    const int t0  = n0 * PP;

    // ---- stage h rows n0 .. n0+FPB (clamped to N-1), float4 loads ----
    const float* hb = h + (size_t)b * NN * TAPS;
    for (int i4 = tid; i4 < (FPB + 1) * (TAPS / 4); i4 += NTHREADS) {
        int r  = i4 >> 6;           // row 0..4
        int k4 = i4 & 63;           // float4 index within row
        int gr = n0 + r;
        if (gr > NN - 1) gr = NN - 1;
        ((float4*)(sh + r * HSTRIDE))[k4] =
            ((const float4*)(hb + (size_t)gr * TAPS))[k4];
    }

    // ---- stage x window x[t0-255 .. t0+320) ----
    const float* xb = x + (size_t)b * TT;
    for (int i = tid; i < XWIN; i += NTHREADS) {
        int g = t0 - (TAPS - 1) + i;
        sx[i] = (g >= 0) ? xb[g] : 0.0f;
    }
    __syncthreads();

    // ---- compute: thread = (kh, lf, lane); RR consecutive outputs, KTH taps ----
    const int kh   = tid >> 6;                 // tap half: 0 -> k 0..127, 1 -> 128..255
    const int lf   = (tid >> 4) & (FPB - 1);   // local frame 0..3
    const int lane = tid & 15;                 // 0..15
    const int p0   = lane * RR;                // phase of first output
    const float* h0 = sh + lf * HSTRIDE + kh * KTH;
    const float* h1 = h0 + HSTRIDE;
    // sx index of x[t] for r=0, shifted so loop tap index starts at 0
    const int base = lf * PP + p0 + (TAPS - 1) - kh * KTH;

    float acc0[RR], acc1[RR];
    #pragma unroll
    for (int r = 0; r < RR; ++r) { acc0[r] = 0.0f; acc1[r] = 0.0f; }

    // sliding x window: xv[j] == sx[base - k - 7 + j], j = 0..11
    float xv[12];
    #pragma unroll
    for (int j = 8; j < 12; ++j) xv[j] = sx[base - 7 + j];

    #pragma unroll
    for (int i = 0; i < KTH / 8; ++i) {
        const int k = i * 8;
        if (i > 0) {   // carry overlap: old j=0..3 become new j=8..11
            xv[8] = xv[0]; xv[9] = xv[1]; xv[10] = xv[2]; xv[11] = xv[3];
        }
        #pragma unroll
        for (int j = 0; j < 8; ++j) xv[j] = sx[base - k - 7 + j];

        #pragma unroll
        for (int d = 0; d < 8; ++d) {
            float c0 = h0[k + d];
            float c1 = h1[k + d];
            #pragma unroll
            for (int r = 0; r < RR; ++r) {
                float xr = xv[r + 7 - d];   // == sx[base + r - (k+d)]
                acc0[r] = fmaf(xr, c0, acc0[r]);
                acc1[r] = fmaf(xr, c1, acc1[r]);
            }
        }
    }

    // ---- combine tap halves, interpolate, store ----
    float* pr = red + (lf * TPF + lane) * (2 * RR);
    if (kh == 1) {
        #pragma unroll
        for (int r = 0; r < RR; ++r) { pr[r] = acc0[r]; pr[RR + r] = acc1[r]; }
    }
    __syncthreads();
    if (kh == 0) {
        float* ob = out + (size_t)b * TT + t0 + lf * PP + p0;
        #pragma unroll
        for (int r = 0; r < RR; ++r) {
            float a0 = acc0[r] + pr[r];
            float a1 = acc1[r] + pr[RR + r];
            float f  = (float)(p0 + r) * (1.0f / PP);
            ob[r] = a0 + f * (a1 - a0);
        }
    }
}

extern "C" void kernel_launch(void* const* d_in, const int* in_sizes, int n_in,
                              void* d_out, int out_size, void* d_ws, size_t ws_size,
                              hipStream_t stream) {
    const float* x = (const float*)d_in[0];
    const float* h = (const float*)d_in[1];
    float* out    = (float*)d_out;
    azdf_kernel<<<BB * CHUNKS, NTHREADS, 0, stream>>>(x, h, out);
}